// Round 16
// baseline (394.697 us; speedup 1.0000x reference)
//
#include <hip/hip_runtime.h>
#include <string.h>
#include <math.h>

typedef unsigned short u16;
typedef __attribute__((ext_vector_type(8))) short short8;
typedef __attribute__((ext_vector_type(4))) float f32x4;

static constexpr int NT_ = 1527;                 // true N == d_model
static constexpr int NP = 1536;                  // padded (12 x 128)
static constexpr int DK = 509;                   // head dim
static constexpr int DKP = 512;                  // padded head dim
static constexpr int NL = 2;                     // layers
static constexpr long long SZp = (long long)NP * NP;      // 2359296
static constexpr long long HS = (long long)NP * DKP;      // 786432
static constexpr long long WSZ = (long long)NT_ * NT_;    // 2331729

__device__ __forceinline__ u16 f2b(float f) {
  unsigned u = __float_as_uint(f);
  return (u16)((u + 0x7FFFu + ((u >> 16) & 1u)) >> 16);
}
__device__ __forceinline__ float b2f(u16 h) { return __uint_as_float(((unsigned)h) << 16); }

__device__ __forceinline__ void gld16(const void* g, void* l) {
  __builtin_amdgcn_global_load_lds((const __attribute__((address_space(1))) void*)g,
                                   (__attribute__((address_space(3))) void*)l, 16, 0, 0);
}

#define BARX() do { __builtin_amdgcn_s_barrier(); __builtin_amdgcn_sched_barrier(0); } while (0)
#define WAITV(n) asm volatile("s_waitcnt vmcnt(" #n ") lgkmcnt(0)" ::: "memory")

// ---------------- MFMA GEMM (always NT: C[i][j] = sum_k A[i][k]*B[j][k]) ----------
// Tile 64(M) x TN(N), BK templated, 4 waves (2x2), double-buffered LDS, counted
// vmcnt, two raw s_barriers per K-step.
// Configs (measured R9/R12/R13): TN=128+BK=32 (24KB) for QKV/SC; TN=64+BK=64
// (32KB) for the rest. EP_QKVP: split-K=2 variant (z = kh*3 + slice, K=768,
// bf16 partials) — TLP probe: 1728 blocks @ MINW=6.
// Staging: linear LDS dest (m104), source chunk-swizzle c^(row&3) matched by read
// swizzle g^(fr&3) (refcheck'd R11-R15). XCD 2D-region block swizzle (R10).
struct GP {
  const u16* A; long long sA; int lda;
  const u16* B; long long sB; int ldb;
  int K;
  u16* C16;                    // bf16 dest
  float* Cf;                   // f32 dest (EP_G1, z-strided by SZp)
  const u16* fT;               // EP_W second operand
  const float* rg; float scale;
  const float *b0, *b1, *b2;   // biases per z
  float* outp;
};

enum { EP_W = 0, EP_QKVP, EP_SC, EP_PV, EP_OP, EP_G1 };

template <int EPI, int TN, int BK, int MINW = 4>
__global__ __launch_bounds__(256, MINW) void mgemm(GP p) {
  constexpr int KH = BK / 32;                   // k-half regions per stage
  constexpr int NFR = TN / 32;                  // B fragments per wave (4 or 2)
  constexpr int CA = KH;                        // A 16B-chunks per thread per stage
  constexpr int CB = KH * TN / 64;              // B chunks per thread per stage
  constexpr int L = CA + CB;                    // gld16 per thread per stage
  constexpr int AREG = 2048;                    // u16 per A region (64x32)
  constexpr int BREG = TN * 32;                 // u16 per B region
  __shared__ __align__(16) u16 As[2][KH * AREG];
  __shared__ __align__(16) u16 Bs[2][KH * BREG];
  const int tid = threadIdx.x;
  const int z = blockIdx.z;
  // split-K decomposition (EP_QKVP only): z = kh*3 + slice
  const int zs = (EPI == EP_QKVP) ? (z % 3) : z;
  const int koff = (EPI == EP_QKVP) ? (z / 3) * 768 : 0;

  // ---- XCD-aware 2D-region swizzle (bijective; guarded) ----
  int bx = blockIdx.x, by = blockIdx.y;
  if ((gridDim.x & 1) == 0 && (gridDim.y & 3) == 0) {
    const int CW = gridDim.x >> 1;
    const int RH = gridDim.y >> 2;
    const int s = by * gridDim.x + bx;
    const int xcd = s & 7;
    const int idx = s >> 3;
    bx = (xcd & 1) * CW + idx % CW;
    by = (xcd >> 1) * RH + idx / CW;
  }
  const int i0 = by * 64;
  const int j0 = bx * TN;

  const u16* A = p.A + p.sA * zs + koff;
  const u16* B = p.B + p.sB * zs + koff;

  // staging pointers (advance by BK per step); source chunk pre-swizzled
  const u16* paP[CA];
  const u16* pbP[CB];
  #pragma unroll
  for (int u = 0; u < CA; ++u) {
    const int kk = u;                           // A region == one 256-slot issue
    const int r = tid >> 2, c = tid & 3;
    paP[u] = A + (long long)(i0 + r) * p.lda + kk * 32 + ((c ^ (r & 3)) << 3);
  }
  #pragma unroll
  for (int u = 0; u < CB; ++u) {
    const int q = u * 256 + tid;
    const int kk = q / (TN * 4);
    const int rem = q - kk * (TN * 4);
    const int r = rem >> 2, c = rem & 3;
    pbP[u] = B + (long long)(j0 + r) * p.ldb + kk * 32 + ((c ^ (r & 3)) << 3);
  }

  const int lane = tid & 63;
  const int wid = tid >> 6;
  const int wrl = (wid >> 1) << 5;              // wave row offset (0/32)
  const int wcl = (wid & 1) * (TN / 2);         // wave col offset
  const int fr = lane & 15;
  const int g = lane >> 4;                      // k-chunk index 0..3
  const int swz = ((g ^ (fr & 3)) << 3);        // read swizzle (matches source)
  const int raofs = (wrl + fr) * 32 + swz;      // within-region offsets
  const int rbofs = (wcl + fr) * 32 + swz;

  const f32x4 zero4 = {0.f, 0.f, 0.f, 0.f};
  f32x4 acc[2][NFR];
  #pragma unroll
  for (int m = 0; m < 2; ++m)
    #pragma unroll
    for (int n = 0; n < NFR; ++n) acc[m][n] = zero4;

  auto issue = [&](int slot) {
    #pragma unroll
    for (int u = 0; u < CA; ++u) {
      gld16(paP[u], &As[slot][(u * 256 + tid) << 3]);
      paP[u] += BK;
    }
    #pragma unroll
    for (int u = 0; u < CB; ++u) {
      gld16(pbP[u], &Bs[slot][(u * 256 + tid) << 3]);
      pbP[u] += BK;
    }
  };

  auto compute = [&](int cur) {
    #pragma unroll
    for (int kk = 0; kk < KH; ++kk) {
      const u16* ra = &As[cur][kk * AREG + raofs];
      const u16* rb = &Bs[cur][kk * BREG + rbofs];
      short8 a[2], b[NFR];
      #pragma unroll
      for (int m = 0; m < 2; ++m) a[m] = *(const short8*)(ra + m * 512);
      #pragma unroll
      for (int n = 0; n < NFR; ++n) b[n] = *(const short8*)(rb + n * 512);
      #pragma unroll
      for (int m = 0; m < 2; ++m)
        #pragma unroll
        for (int n = 0; n < NFR; ++n)
          acc[m][n] = __builtin_amdgcn_mfma_f32_16x16x32_bf16(a[m], b[n], acc[m][n], 0, 0, 0);
    }
  };

  const int nsteps = p.K / BK;
  issue(0);                                     // prologue: stage tile 0

  int cur = 0;
  for (int t = 0; t < nsteps - 1; ++t) {
    const int nb = cur ^ 1;
    issue(nb);                                  // prefetch next (stays in flight)
    if (L == 6) { WAITV(6); } else if (L == 4) { WAITV(4); } else if (L == 3) { WAITV(3); }
    else { WAITV(2); }
    BARX();
    compute(cur);
    BARX();                                     // all waves done reading buf[cur]
    cur = nb;
  }
  WAITV(0);
  BARX();
  compute(cur);

  // epilogue: C/D layout col = lane&15, row = (lane>>4)*4 + reg  [m91-verified]
  const int r0 = (lane >> 4) << 2;
  #pragma unroll
  for (int m = 0; m < 2; ++m) {
    #pragma unroll
    for (int rr = 0; rr < 4; ++rr) {
      const int gi = i0 + wrl + m * 16 + r0 + rr;
      #pragma unroll
      for (int n = 0; n < NFR; ++n) {
        const int gj = j0 + wcl + n * 16 + fr;
        const float x = acc[m][n][rr];
        if (EPI == EP_W) {
          const long long o = (long long)gi * NP + gj;
          const float v = (gi < NT_ && gj < NT_) ? 0.3f * x + 0.7f * b2f(p.fT[o]) : 0.f;
          p.C16[o] = f2b(v);
        } else if (EPI == EP_QKVP) {
          // raw bf16 partial; combine kernel applies bias + head split + masks
          p.C16[(long long)z * SZp + (long long)gi * NP + gj] = f2b(x);
        } else if (EPI == EP_SC) {
          // bf16 scores, compact [NP][NP]; pads -> 0
          const long long o = (long long)gi * NP + gj;
          const float v = (gi < NT_ && gj < NT_) ? x * p.scale * p.rg[o] : 0.f;
          p.C16[(long long)z * SZp + o] = f2b(v);
        } else if (EPI == EP_PV) {
          if (gj < DK) {
            p.C16[(long long)gi * NP + z * DK + gj] = f2b((gi < NT_) ? x : 0.f);
          }
        } else if (EPI == EP_OP) {
          const long long o = (long long)gi * NP + gj;
          float v = 0.f;
          if (gi < NT_ && gj < NT_) v = b2f(p.C16[o]) + x + p.b0[gj];
          p.C16[o] = f2b(v);
        } else {  // EP_G1 (z-batched gate GEMMs, f32 out)
          const long long o = (long long)gi * NP + gj;
          p.Cf[(long long)z * SZp + o] = (gi < NT_ && gj < NT_) ? x : 0.f;
        }
      }
    }
  }
}

// ---------------- support kernels (ILP-4 rows per thread, coalesced loads) -------
__global__ __launch_bounds__(256) void rowsum_inv(const float* __restrict__ A,
                                                  float* __restrict__ inv) {
  const int r = blockIdx.x;
  const float* p = A + (long long)r * NT_;
  float s = 0.f;
  for (int j = threadIdx.x; j < NT_; j += 256)
    if (j != r) s += p[j];
  #pragma unroll
  for (int off = 32; off; off >>= 1) s += __shfl_xor(s, off);
  __shared__ float red[4];
  const int wid = threadIdx.x >> 6, lane = threadIdx.x & 63;
  if (lane == 0) red[wid] = s;
  __syncthreads();
  if (threadIdx.x == 0) {
    const float t = red[0] + red[1] + red[2] + red[3];
    inv[r] = 1.f / (t == 0.f ? 1.f : t);
  }
}

// hb = padded bf16 of feature  (4 rows/thread)
__global__ __launch_bounds__(256) void prep_feat(const float* __restrict__ f,
                                                 u16* __restrict__ hb) {
  const int j = blockIdx.x * 256 + threadIdx.x;
  const int i0 = blockIdx.y * 4;
  #pragma unroll
  for (int r = 0; r < 4; ++r) {
    const int i = i0 + r;
    const float v = (i < NT_ && j < NT_) ? f[(long long)i * NT_ + j] : 0.f;
    hb[(long long)i * NP + j] = f2b(v);
  }
}

// PT[i][k] = (i!=k)*feature[k][i]*inv[k]; fT[i][k] = feature[k][i]   (bf16, padded)
__global__ __launch_bounds__(256) void build_pt(const float* __restrict__ f,
                                                const float* __restrict__ inv,
                                                u16* __restrict__ PT, u16* __restrict__ fT) {
  __shared__ float t[32][33];
  const int bx = blockIdx.x * 32;   // i
  const int by = blockIdx.y * 32;   // k
  const int tx = threadIdx.x & 31;
  const int ty = threadIdx.x >> 5;
  #pragma unroll
  for (int rr = 0; rr < 32; rr += 8) {
    const int k = by + ty + rr, i = bx + tx;
    t[ty + rr][tx] = (k < NT_ && i < NT_) ? f[(long long)k * NT_ + i] : 0.f;
  }
  __syncthreads();
  const int k = by + tx;
  const float ik = (k < NT_) ? inv[k] : 0.f;
  #pragma unroll
  for (int rr = 0; rr < 32; rr += 8) {
    const int i = bx + ty + rr;
    const float v = t[tx][ty + rr];
    const long long o = (long long)i * NP + k;
    fT[o] = f2b(v);
    PT[o] = f2b((i == k) ? 0.f : v * ik);
  }
}

// weight convert: dst[z] = padded bf16 of src_z[i*lds + j]  (4 rows/thread)
__global__ __launch_bounds__(256) void conv_w(const float* s0, const float* s1,
                                              const float* s2, const float* s3,
                                              int lds, u16* __restrict__ dst) {
  const int z = blockIdx.z;
  const float* s = (z == 0) ? s0 : (z == 1) ? s1 : (z == 2) ? s2 : s3;
  const int j = blockIdx.x * 256 + threadIdx.x;
  const int i0 = blockIdx.y * 4;
  u16* d = dst + (long long)z * SZp + (long long)i0 * NP + j;
  #pragma unroll
  for (int r = 0; r < 4; ++r) {
    const int i = i0 + r;
    const float v = (i < NT_ && j < NT_) ? s[(long long)i * lds + j] : 0.f;
    d[(long long)r * NP] = f2b(v);
  }
}

// QKV split-K combine: dst[z][h][i][hc] = part0 + part1 + bias  (4 rows/thread)
__global__ __launch_bounds__(256) void qkv_combine(const u16* __restrict__ part,
                                                   const float* __restrict__ b0,
                                                   const float* __restrict__ b1,
                                                   const float* __restrict__ b2,
                                                   u16* __restrict__ dst) {
  const int z = blockIdx.z;
  const float* bb = (z == 0) ? b0 : (z == 1) ? b1 : b2;
  const int j = blockIdx.x * 256 + threadIdx.x;
  if (j >= NT_) return;
  const int h = (j >= 1018) ? 2 : (j >= 509) ? 1 : 0;
  const int hc = j - h * 509;
  const float bj = bb[j];
  const int i0 = blockIdx.y * 4;
  const u16* p0 = part + (long long)z * SZp;
  const u16* p1 = part + (long long)(z + 3) * SZp;
  u16* d = dst + (long long)z * SZp + (long long)h * HS + hc;
  #pragma unroll
  for (int r = 0; r < 4; ++r) {
    const int i = i0 + r;
    const long long o = (long long)i * NP + j;
    const float v = (i < NT_) ? b2f(p0[o]) + b2f(p1[o]) + bj : 0.f;
    d[(long long)i * DKP] = f2b(v);
  }
}

// rg = e0*feature + e1*W1T + e2*W2T (f32, padded zeros; 4 rows/thread)
__global__ __launch_bounds__(256) void rg_elem(const float* __restrict__ f,
                                               const u16* __restrict__ W1T,
                                               const u16* __restrict__ W2T,
                                               const float* __restrict__ etas,
                                               float* __restrict__ rg) {
  const int j = blockIdx.x * 256 + threadIdx.x;
  const int i0 = blockIdx.y * 4;
  const float e0 = etas[0], e1 = etas[1], e2 = etas[2];
  #pragma unroll
  for (int r = 0; r < 4; ++r) {
    const int i = i0 + r;
    const long long o = (long long)i * NP + j;
    float v = 0.f;
    if (i < NT_ && j < NT_)
      v = e0 * f[(long long)i * NT_ + j] + e1 * b2f(W1T[o]) + e2 * b2f(W2T[o]);
    rg[o] = v;
  }
}

// bf16 tile transpose: [NP][DKP] -> [DKP][NP], z-batched (head slices)
__global__ __launch_bounds__(256) void tr_b16(const u16* __restrict__ S, u16* __restrict__ D) {
  const int z = blockIdx.z;
  const u16* s = S + (long long)z * HS;
  u16* d = D + (long long)z * HS;
  __shared__ u16 t[32][33];
  const int bx = blockIdx.x * 32;  // col of src
  const int by = blockIdx.y * 32;  // row of src
  const int tx = threadIdx.x & 31, ty = threadIdx.x >> 5;
  #pragma unroll
  for (int rr = 0; rr < 32; rr += 8)
    t[ty + rr][tx] = s[(long long)(by + ty + rr) * DKP + bx + tx];
  __syncthreads();
  #pragma unroll
  for (int rr = 0; rr < 32; rr += 8)
    d[(long long)(bx + ty + rr) * NP + by + tx] = t[tx][ty + rr];
}

// row softmax over bf16 scores, in place. Thread t owns cols 8t..8t+7 (t<192).
__global__ __launch_bounds__(256) void softmax_k(u16* __restrict__ S) {
  const int h = blockIdx.y;
  const int i = blockIdx.x;
  u16* sp = S + (long long)h * SZp + (long long)i * NP;
  const int tid = threadIdx.x;
  const bool own = (tid < 192);
  const bool act = own && (i < NT_);
  short8 raw = {};
  if (act) raw = *(const short8*)(sp + tid * 8);
  float v[8];
  float mx = -3.0e38f;
  #pragma unroll
  for (int c = 0; c < 8; ++c) {
    const int j = tid * 8 + c;
    v[c] = (act && j < NT_) ? b2f((u16)raw[c]) : -3.0e38f;
    mx = fmaxf(mx, v[c]);
  }
  #pragma unroll
  for (int off = 32; off; off >>= 1) mx = fmaxf(mx, __shfl_xor(mx, off));
  __shared__ float red[4];
  const int wid = tid >> 6, lane = tid & 63;
  if (lane == 0) red[wid] = mx;
  __syncthreads();
  mx = fmaxf(fmaxf(red[0], red[1]), fmaxf(red[2], red[3]));
  __syncthreads();
  float s = 0.f;
  #pragma unroll
  for (int c = 0; c < 8; ++c) { v[c] = __expf(v[c] - mx); s += v[c]; }
  #pragma unroll
  for (int off = 32; off; off >>= 1) s += __shfl_xor(s, off);
  if (lane == 0) red[wid] = s;
  __syncthreads();
  s = red[0] + red[1] + red[2] + red[3];
  const float invs = 1.f / s;
  if (own) {
    short8 ov;
    #pragma unroll
    for (int c = 0; c < 8; ++c)
      ov[c] = (short)((i < NT_) ? f2b(v[c] * invs) : (u16)0);
    *(short8*)(sp + tid * 8) = ov;
  }
}

// final gate: out = (1-g)*feature + g*faeture  (4 rows/thread)
__global__ __launch_bounds__(256) void gate_elem(const float* __restrict__ g1,
                                                 const float* __restrict__ g2,
                                                 const float* __restrict__ gb,
                                                 const float* __restrict__ f1,
                                                 const float* __restrict__ f2,
                                                 float* __restrict__ out) {
  const int j = blockIdx.x * 256 + threadIdx.x;
  const int i0 = blockIdx.y * 4;
  if (j >= NT_) return;
  const float gbj = gb[j];
  #pragma unroll
  for (int r = 0; r < 4; ++r) {
    const int i = i0 + r;
    if (i >= NT_) break;
    const long long o = (long long)i * NP + j;
    const float t = g1[o] + g2[o] + gbj;
    const float g = 1.f / (1.f + __expf(-t));
    const long long oo = (long long)i * NT_ + j;
    out[oo] = (1.f - g) * f1[oo] + g * f2[oo];
  }
}

// zero head-pad cols of Q/K/V slots and tail cols of ctxp (once per call)
__global__ __launch_bounds__(256) void zero_pads(u16* __restrict__ qkv, u16* __restrict__ ctxp) {
  const int idx = blockIdx.x * 256 + threadIdx.x;
  if (idx < 41472) {
    const int buf = idx / 13824;
    const int r1 = idx % 13824;
    const int h = r1 / 4608;
    const int r2 = r1 % 4608;
    const int row = r2 / 3;
    const int c = DK + r2 % 3;
    qkv[(long long)buf * SZp + (long long)h * HS + (long long)row * DKP + c] = 0;
  } else {
    const int k = idx - 41472;
    const int row = k / 9;
    const int c = NT_ + k % 9;
    ctxp[(long long)row * NP + c] = 0;
  }
}

static inline GP mk() { GP p; memset(&p, 0, sizeof(p)); return p; }

extern "C" void kernel_launch(void* const* d_in, const int* in_sizes, int n_in,
                              void* d_out, int out_size, void* d_ws, size_t ws_size,
                              hipStream_t stream) {
  (void)in_sizes; (void)n_in; (void)out_size; (void)ws_size;
  const float* feature = (const float*)d_in[0];
  const float* faeture = (const float*)d_in[1];
  const float* Wq = (const float*)d_in[2];
  const float* bq = (const float*)d_in[3];
  const float* Wk = (const float*)d_in[4];
  const float* bk = (const float*)d_in[5];
  const float* Wv = (const float*)d_in[6];
  const float* bv = (const float*)d_in[7];
  const float* Wo = (const float*)d_in[8];
  const float* bo = (const float*)d_in[9];
  const float* gW = (const float*)d_in[10];
  const float* gb = (const float*)d_in[11];
  const float* etas = (const float*)d_in[12];
  float* out = (float*)d_out;

  // workspace map (peak ~82.7 MB)
  u16* ub = (u16*)d_ws;
  u16* slotA = ub + 0 * SZp;         // PT / Q[3 heads] / gate: feature bf16
  u16* slotB = ub + 1 * SZp;         // fT / K
  u16* slotC = ub + 2 * SZp;         // W1T / V
  u16* slotD = ub + 3 * SZp;         // W2T / V^T
  u16* Hb16  = ub + 4 * SZp;
  u16* ctxp  = ub + 5 * SZp;
  u16* Wb    = ub + 6 * SZp;         // 4 slots (Wq,Wk,Wv,Wo / G1,G2)
  float* fa = (float*)(ub + 10 * SZp);
  float* S0 = fa;                    // scores (bf16 view) / QKV partials x6 / gacc f32 x2
  u16* Sb = (u16*)fa;
  float* rg = fa + 3 * SZp;
  float* inv = fa + 4 * SZp;

  const float scale = 1.0f / sqrtf((float)DK);
  const dim3 blk(256);

  // ---- prep + RWR ----
  hipLaunchKernelGGL(rowsum_inv, dim3(NT_), blk, 0, stream, feature, inv);
  hipLaunchKernelGGL(prep_feat, dim3(6, 384), blk, 0, stream, feature, Hb16);
  hipLaunchKernelGGL(build_pt, dim3(48, 48), blk, 0, stream, feature, inv, slotA, slotB);
  {
    GP p = mk();  // W1T = 0.3*(E^T P) + 0.7*E^T
    p.A = slotB; p.lda = NP; p.B = slotA; p.ldb = NP; p.K = NP;
    p.C16 = slotC; p.fT = slotB;
    hipLaunchKernelGGL((mgemm<EP_W, 64, 64>), dim3(24, 24, 1), blk, 0, stream, p);
  }
  {
    GP p = mk();  // W2T = 0.3*(W1T P) + 0.7*E^T
    p.A = slotC; p.lda = NP; p.B = slotA; p.ldb = NP; p.K = NP;
    p.C16 = slotD; p.fT = slotB;
    hipLaunchKernelGGL((mgemm<EP_W, 64, 64>), dim3(24, 24, 1), blk, 0, stream, p);
  }
  hipLaunchKernelGGL(rg_elem, dim3(6, 384), blk, 0, stream, feature, slotC, slotD, etas, rg);
  hipLaunchKernelGGL(zero_pads, dim3(216), blk, 0, stream, slotA, ctxp);

  // ---- layers ----
  for (int l = 0; l < NL; ++l) {
    const long long wofs = (long long)l * WSZ;
    const long long bofs = (long long)l * NT_;
    hipLaunchKernelGGL(conv_w, dim3(6, 384, 4), blk, 0, stream,
                       Wq + wofs, Wk + wofs, Wv + wofs, Wo + wofs, NT_, Wb);
    {
      GP p = mk();  // QKV split-K=2: partials[kh*3+zs] = H[:,kh] @ W[zs][:,kh]^T
      p.A = Hb16; p.sA = 0; p.lda = NP;
      p.B = Wb; p.sB = SZp; p.ldb = NP; p.K = 768;
      p.C16 = Sb;
      hipLaunchKernelGGL((mgemm<EP_QKVP, 128, 32, 6>), dim3(12, 24, 6), blk, 0, stream, p);
    }
    hipLaunchKernelGGL(qkv_combine, dim3(6, 384, 3), blk, 0, stream,
                       Sb, bq + bofs, bk + bofs, bv + bofs, slotA);
    {
      GP p = mk();  // S_h = bf16((Q_h K_h^T * scale) .* rg)
      p.A = slotA; p.sA = HS; p.lda = DKP;
      p.B = slotB; p.sB = HS; p.ldb = DKP; p.K = DKP;
      p.C16 = Sb; p.rg = rg; p.scale = scale;
      hipLaunchKernelGGL((mgemm<EP_SC, 128, 32, 6>), dim3(12, 24, 3), blk, 0, stream, p);
    }
    hipLaunchKernelGGL(softmax_k, dim3(NP, 3), blk, 0, stream, Sb);
    hipLaunchKernelGGL(tr_b16, dim3(16, 48, 3), blk, 0, stream, slotC, slotD);
    {
      GP p = mk();  // ctx_h = attn_h @ V_h   (A = compact bf16 attn, B = V^T)
      p.A = Sb; p.sA = SZp; p.lda = NP;
      p.B = slotD; p.sB = HS; p.ldb = NP; p.K = NP;
      p.C16 = ctxp;
      hipLaunchKernelGGL((mgemm<EP_PV, 64, 64>), dim3(8, 24, 3), blk, 0, stream, p);
    }
    {
      GP p = mk();  // H = H + ctx @ Wo^T + bo  (in-place bf16 H)
      p.A = ctxp; p.sA = 0; p.lda = NP;
      p.B = Wb + 3 * SZp; p.sB = 0; p.ldb = NP; p.K = NP;
      p.C16 = Hb16; p.b0 = bo + bofs;
      hipLaunchKernelGGL((mgemm<EP_OP, 64, 64>), dim3(24, 24, 1), blk, 0, stream, p);
    }
  }

  // ---- gate (z=2 batched GEMM + elementwise blend) ----
  hipLaunchKernelGGL(conv_w, dim3(6, 384, 2), blk, 0, stream,
                     gW, gW + NT_, gW, gW, 2 * NT_, Wb);
  hipLaunchKernelGGL(prep_feat, dim3(6, 384), blk, 0, stream, feature, slotA);
  {
    GP p = mk();  // z0: H@G1^T -> S0[0] ; z1: feature@G2^T -> S0[1]
    p.A = Hb16; p.sA = -(4 * SZp); p.lda = NP;   // z=1 selects slotA
    p.B = Wb; p.sB = SZp; p.ldb = NP; p.K = NP;
    p.Cf = S0;
    hipLaunchKernelGGL((mgemm<EP_G1, 64, 64>), dim3(24, 24, 2), blk, 0, stream, p);
  }
  hipLaunchKernelGGL(gate_elem, dim3(6, 382), blk, 0, stream,
                     S0, S0 + SZp, gb, feature, faeture, out);
}

// Round 17
// 381.168 us; speedup vs baseline: 1.0355x; 1.0355x over previous
//
#include <hip/hip_runtime.h>
#include <string.h>
#include <math.h>

typedef unsigned short u16;
typedef __attribute__((ext_vector_type(8))) short short8;
typedef __attribute__((ext_vector_type(4))) float f32x4;

static constexpr int NT_ = 1527;                 // true N == d_model
static constexpr int NP = 1536;                  // padded (12 x 128)
static constexpr int DK = 509;                   // head dim
static constexpr int DKP = 512;                  // padded head dim
static constexpr int NL = 2;                     // layers
static constexpr long long SZp = (long long)NP * NP;      // 2359296
static constexpr long long HS = (long long)NP * DKP;      // 786432
static constexpr long long WSZ = (long long)NT_ * NT_;    // 2331729

__device__ __forceinline__ u16 f2b(float f) {
  unsigned u = __float_as_uint(f);
  return (u16)((u + 0x7FFFu + ((u >> 16) & 1u)) >> 16);
}
__device__ __forceinline__ float b2f(u16 h) { return __uint_as_float(((unsigned)h) << 16); }

__device__ __forceinline__ void gld16(const void* g, void* l) {
  __builtin_amdgcn_global_load_lds((const __attribute__((address_space(1))) void*)g,
                                   (__attribute__((address_space(3))) void*)l, 16, 0, 0);
}

#define BARX() do { __builtin_amdgcn_s_barrier(); __builtin_amdgcn_sched_barrier(0); } while (0)
#define WAITV(n) asm volatile("s_waitcnt vmcnt(" #n ") lgkmcnt(0)" ::: "memory")

// ---------------- MFMA GEMM (always NT: C[i][j] = sum_k A[i][k]*B[j][k]) ----------
// Tile 64(M) x TN(N), BK templated (32 or 64), 4 waves (2x2), double-buffered LDS,
// counted vmcnt, two raw s_barriers per K-step.
// Per-shape best configs (measured R9/R12/R13):
//   TN=128 + BK=32 -> 24KB LDS (QKV/SC)
//   TN=64  + BK=64 -> 32KB LDS (EP_W/PV/OP/G1)
// Staging: linear LDS dest (m104), source chunk-swizzle c^(row&3) matched by read
// swizzle g^(fr&3) (refcheck'd R11-R15). XCD 2D-region block swizzle (R10).
struct GP {
  const u16* A; long long sA; int lda;
  const u16* B; long long sB; int ldb;
  int K;
  u16* C16;                    // bf16 dest (EP_W / EP_QKV / EP_SC / EP_PV / EP_OP)
  float* Cf;                   // f32 dest (EP_G1, z-strided by SZp)
  const u16* fT;               // EP_W second operand
  const float* rg; float scale;
  const float *b0, *b1, *b2;   // biases per z
  float* outp;
};

enum { EP_W = 0, EP_QKV, EP_SC, EP_PV, EP_OP, EP_G1 };

template <int EPI, int TN, int BK>
__global__ __launch_bounds__(256, 4) void mgemm(GP p) {
  constexpr int KH = BK / 32;                   // k-half regions per stage
  constexpr int NFR = TN / 32;                  // B fragments per wave (4 or 2)
  constexpr int CA = KH;                        // A 16B-chunks per thread per stage
  constexpr int CB = KH * TN / 64;              // B chunks per thread per stage
  constexpr int L = CA + CB;                    // gld16 per thread per stage
  constexpr int AREG = 2048;                    // u16 per A region (64x32)
  constexpr int BREG = TN * 32;                 // u16 per B region
  __shared__ __align__(16) u16 As[2][KH * AREG];
  __shared__ __align__(16) u16 Bs[2][KH * BREG];
  const int tid = threadIdx.x;
  const int z = blockIdx.z;

  // ---- XCD-aware 2D-region swizzle (bijective; guarded) ----
  int bx = blockIdx.x, by = blockIdx.y;
  if ((gridDim.x & 1) == 0 && (gridDim.y & 3) == 0) {
    const int CW = gridDim.x >> 1;
    const int RH = gridDim.y >> 2;
    const int s = by * gridDim.x + bx;
    const int xcd = s & 7;
    const int idx = s >> 3;
    bx = (xcd & 1) * CW + idx % CW;
    by = (xcd >> 1) * RH + idx / CW;
  }
  const int i0 = by * 64;
  const int j0 = bx * TN;

  const u16* A = p.A + p.sA * z;
  const u16* B = p.B + p.sB * z;

  // staging pointers (advance by BK per step); source chunk pre-swizzled
  const u16* paP[CA];
  const u16* pbP[CB];
  #pragma unroll
  for (int u = 0; u < CA; ++u) {
    const int kk = u;                           // A region == one 256-slot issue
    const int r = tid >> 2, c = tid & 3;
    paP[u] = A + (long long)(i0 + r) * p.lda + kk * 32 + ((c ^ (r & 3)) << 3);
  }
  #pragma unroll
  for (int u = 0; u < CB; ++u) {
    const int q = u * 256 + tid;
    const int kk = q / (TN * 4);
    const int rem = q - kk * (TN * 4);
    const int r = rem >> 2, c = rem & 3;
    pbP[u] = B + (long long)(j0 + r) * p.ldb + kk * 32 + ((c ^ (r & 3)) << 3);
  }

  const int lane = tid & 63;
  const int wid = tid >> 6;
  const int wrl = (wid >> 1) << 5;              // wave row offset (0/32)
  const int wcl = (wid & 1) * (TN / 2);         // wave col offset
  const int fr = lane & 15;
  const int g = lane >> 4;                      // k-chunk index 0..3
  const int swz = ((g ^ (fr & 3)) << 3);        // read swizzle (matches source)
  const int raofs = (wrl + fr) * 32 + swz;      // within-region offsets
  const int rbofs = (wcl + fr) * 32 + swz;

  const f32x4 zero4 = {0.f, 0.f, 0.f, 0.f};
  f32x4 acc[2][NFR];
  #pragma unroll
  for (int m = 0; m < 2; ++m)
    #pragma unroll
    for (int n = 0; n < NFR; ++n) acc[m][n] = zero4;

  auto issue = [&](int slot) {
    #pragma unroll
    for (int u = 0; u < CA; ++u) {
      gld16(paP[u], &As[slot][(u * 256 + tid) << 3]);
      paP[u] += BK;
    }
    #pragma unroll
    for (int u = 0; u < CB; ++u) {
      gld16(pbP[u], &Bs[slot][(u * 256 + tid) << 3]);
      pbP[u] += BK;
    }
  };

  auto compute = [&](int cur) {
    #pragma unroll
    for (int kk = 0; kk < KH; ++kk) {
      const u16* ra = &As[cur][kk * AREG + raofs];
      const u16* rb = &Bs[cur][kk * BREG + rbofs];
      short8 a[2], b[NFR];
      #pragma unroll
      for (int m = 0; m < 2; ++m) a[m] = *(const short8*)(ra + m * 512);
      #pragma unroll
      for (int n = 0; n < NFR; ++n) b[n] = *(const short8*)(rb + n * 512);
      #pragma unroll
      for (int m = 0; m < 2; ++m)
        #pragma unroll
        for (int n = 0; n < NFR; ++n)
          acc[m][n] = __builtin_amdgcn_mfma_f32_16x16x32_bf16(a[m], b[n], acc[m][n], 0, 0, 0);
    }
  };

  const int nsteps = p.K / BK;
  issue(0);                                     // prologue: stage tile 0

  int cur = 0;
  for (int t = 0; t < nsteps - 1; ++t) {
    const int nb = cur ^ 1;
    issue(nb);                                  // prefetch next (stays in flight)
    if (L == 6) { WAITV(6); } else if (L == 4) { WAITV(4); } else if (L == 3) { WAITV(3); }
    else { WAITV(2); }
    BARX();
    compute(cur);
    BARX();                                     // all waves done reading buf[cur]
    cur = nb;
  }
  WAITV(0);
  BARX();
  compute(cur);

  // epilogue: C/D layout col = lane&15, row = (lane>>4)*4 + reg  [m91-verified]
  const int r0 = (lane >> 4) << 2;
  const float* bz = (z == 0) ? p.b0 : (z == 1) ? p.b1 : p.b2;
  #pragma unroll
  for (int m = 0; m < 2; ++m) {
    #pragma unroll
    for (int rr = 0; rr < 4; ++rr) {
      const int gi = i0 + wrl + m * 16 + r0 + rr;
      #pragma unroll
      for (int n = 0; n < NFR; ++n) {
        const int gj = j0 + wcl + n * 16 + fr;
        const float x = acc[m][n][rr];
        if (EPI == EP_W) {
          const long long o = (long long)gi * NP + gj;
          const float v = (gi < NT_ && gj < NT_) ? 0.3f * x + 0.7f * b2f(p.fT[o]) : 0.f;
          p.C16[o] = f2b(v);
        } else if (EPI == EP_QKV) {
          if (gj < NT_) {
            const int h = (gj >= 1018) ? 2 : (gj >= 509) ? 1 : 0;
            const int hc = gj - h * 509;
            const float v = (gi < NT_) ? x + bz[gj] : 0.f;
            p.C16[(long long)z * SZp + (long long)h * HS + (long long)gi * DKP + hc] = f2b(v);
          }
        } else if (EPI == EP_SC) {
          // bf16 scores, compact [NP][NP]; pads -> 0
          const long long o = (long long)gi * NP + gj;
          const float v = (gi < NT_ && gj < NT_) ? x * p.scale * p.rg[o] : 0.f;
          p.C16[(long long)z * SZp + o] = f2b(v);
        } else if (EPI == EP_PV) {
          if (gj < DK) {
            p.C16[(long long)gi * NP + z * DK + gj] = f2b((gi < NT_) ? x : 0.f);
          }
        } else if (EPI == EP_OP) {
          const long long o = (long long)gi * NP + gj;
          float v = 0.f;
          if (gi < NT_ && gj < NT_) v = b2f(p.C16[o]) + x + p.b0[gj];
          p.C16[o] = f2b(v);
        } else {  // EP_G1 (z-batched gate GEMMs, f32 out)
          const long long o = (long long)gi * NP + gj;
          p.Cf[(long long)z * SZp + o] = (gi < NT_ && gj < NT_) ? x : 0.f;
        }
      }
    }
  }
}

// ---------------- support kernels (ILP-4 rows per thread, coalesced loads) -------
__global__ __launch_bounds__(256) void rowsum_inv(const float* __restrict__ A,
                                                  float* __restrict__ inv) {
  const int r = blockIdx.x;
  const float* p = A + (long long)r * NT_;
  float s = 0.f;
  for (int j = threadIdx.x; j < NT_; j += 256)
    if (j != r) s += p[j];
  #pragma unroll
  for (int off = 32; off; off >>= 1) s += __shfl_xor(s, off);
  __shared__ float red[4];
  const int wid = threadIdx.x >> 6, lane = threadIdx.x & 63;
  if (lane == 0) red[wid] = s;
  __syncthreads();
  if (threadIdx.x == 0) {
    const float t = red[0] + red[1] + red[2] + red[3];
    inv[r] = 1.f / (t == 0.f ? 1.f : t);
  }
}

// hb = padded bf16 of feature  (4 rows/thread)
__global__ __launch_bounds__(256) void prep_feat(const float* __restrict__ f,
                                                 u16* __restrict__ hb) {
  const int j = blockIdx.x * 256 + threadIdx.x;
  const int i0 = blockIdx.y * 4;
  #pragma unroll
  for (int r = 0; r < 4; ++r) {
    const int i = i0 + r;
    const float v = (i < NT_ && j < NT_) ? f[(long long)i * NT_ + j] : 0.f;
    hb[(long long)i * NP + j] = f2b(v);
  }
}

// PT[i][k] = (i!=k)*feature[k][i]*inv[k]; fT[i][k] = feature[k][i]   (bf16, padded)
__global__ __launch_bounds__(256) void build_pt(const float* __restrict__ f,
                                                const float* __restrict__ inv,
                                                u16* __restrict__ PT, u16* __restrict__ fT) {
  __shared__ float t[32][33];
  const int bx = blockIdx.x * 32;   // i
  const int by = blockIdx.y * 32;   // k
  const int tx = threadIdx.x & 31;
  const int ty = threadIdx.x >> 5;
  #pragma unroll
  for (int rr = 0; rr < 32; rr += 8) {
    const int k = by + ty + rr, i = bx + tx;
    t[ty + rr][tx] = (k < NT_ && i < NT_) ? f[(long long)k * NT_ + i] : 0.f;
  }
  __syncthreads();
  const int k = by + tx;
  const float ik = (k < NT_) ? inv[k] : 0.f;
  #pragma unroll
  for (int rr = 0; rr < 32; rr += 8) {
    const int i = bx + ty + rr;
    const float v = t[tx][ty + rr];
    const long long o = (long long)i * NP + k;
    fT[o] = f2b(v);
    PT[o] = f2b((i == k) ? 0.f : v * ik);
  }
}

// weight convert: dst[z] = padded bf16 of src_z[i*lds + j]  (4 rows/thread)
__global__ __launch_bounds__(256) void conv_w(const float* s0, const float* s1,
                                              const float* s2, const float* s3,
                                              int lds, u16* __restrict__ dst) {
  const int z = blockIdx.z;
  const float* s = (z == 0) ? s0 : (z == 1) ? s1 : (z == 2) ? s2 : s3;
  const int j = blockIdx.x * 256 + threadIdx.x;
  const int i0 = blockIdx.y * 4;
  u16* d = dst + (long long)z * SZp + (long long)i0 * NP + j;
  #pragma unroll
  for (int r = 0; r < 4; ++r) {
    const int i = i0 + r;
    const float v = (i < NT_ && j < NT_) ? s[(long long)i * lds + j] : 0.f;
    d[(long long)r * NP] = f2b(v);
  }
}

// rg = e0*feature + e1*W1T + e2*W2T (f32, padded zeros; 4 rows/thread)
__global__ __launch_bounds__(256) void rg_elem(const float* __restrict__ f,
                                               const u16* __restrict__ W1T,
                                               const u16* __restrict__ W2T,
                                               const float* __restrict__ etas,
                                               float* __restrict__ rg) {
  const int j = blockIdx.x * 256 + threadIdx.x;
  const int i0 = blockIdx.y * 4;
  const float e0 = etas[0], e1 = etas[1], e2 = etas[2];
  #pragma unroll
  for (int r = 0; r < 4; ++r) {
    const int i = i0 + r;
    const long long o = (long long)i * NP + j;
    float v = 0.f;
    if (i < NT_ && j < NT_)
      v = e0 * f[(long long)i * NT_ + j] + e1 * b2f(W1T[o]) + e2 * b2f(W2T[o]);
    rg[o] = v;
  }
}

// bf16 tile transpose: [NP][DKP] -> [DKP][NP], z-batched (head slices)
__global__ __launch_bounds__(256) void tr_b16(const u16* __restrict__ S, u16* __restrict__ D) {
  const int z = blockIdx.z;
  const u16* s = S + (long long)z * HS;
  u16* d = D + (long long)z * HS;
  __shared__ u16 t[32][33];
  const int bx = blockIdx.x * 32;  // col of src
  const int by = blockIdx.y * 32;  // row of src
  const int tx = threadIdx.x & 31, ty = threadIdx.x >> 5;
  #pragma unroll
  for (int rr = 0; rr < 32; rr += 8)
    t[ty + rr][tx] = s[(long long)(by + ty + rr) * DKP + bx + tx];
  __syncthreads();
  #pragma unroll
  for (int rr = 0; rr < 32; rr += 8)
    d[(long long)(bx + ty + rr) * NP + by + tx] = t[tx][ty + rr];
}

// row softmax over bf16 scores, in place. Thread t owns cols 8t..8t+7 (t<192).
__global__ __launch_bounds__(256) void softmax_k(u16* __restrict__ S) {
  const int h = blockIdx.y;
  const int i = blockIdx.x;
  u16* sp = S + (long long)h * SZp + (long long)i * NP;
  const int tid = threadIdx.x;
  const bool own = (tid < 192);
  const bool act = own && (i < NT_);
  short8 raw = {};
  if (act) raw = *(const short8*)(sp + tid * 8);
  float v[8];
  float mx = -3.0e38f;
  #pragma unroll
  for (int c = 0; c < 8; ++c) {
    const int j = tid * 8 + c;
    v[c] = (act && j < NT_) ? b2f((u16)raw[c]) : -3.0e38f;
    mx = fmaxf(mx, v[c]);
  }
  #pragma unroll
  for (int off = 32; off; off >>= 1) mx = fmaxf(mx, __shfl_xor(mx, off));
  __shared__ float red[4];
  const int wid = tid >> 6, lane = tid & 63;
  if (lane == 0) red[wid] = mx;
  __syncthreads();
  mx = fmaxf(fmaxf(red[0], red[1]), fmaxf(red[2], red[3]));
  __syncthreads();
  float s = 0.f;
  #pragma unroll
  for (int c = 0; c < 8; ++c) { v[c] = __expf(v[c] - mx); s += v[c]; }
  #pragma unroll
  for (int off = 32; off; off >>= 1) s += __shfl_xor(s, off);
  if (lane == 0) red[wid] = s;
  __syncthreads();
  s = red[0] + red[1] + red[2] + red[3];
  const float invs = 1.f / s;
  if (own) {
    short8 ov;
    #pragma unroll
    for (int c = 0; c < 8; ++c)
      ov[c] = (short)((i < NT_) ? f2b(v[c] * invs) : (u16)0);
    *(short8*)(sp + tid * 8) = ov;
  }
}

// final gate: out = (1-g)*feature + g*faeture  (4 rows/thread)
__global__ __launch_bounds__(256) void gate_elem(const float* __restrict__ g1,
                                                 const float* __restrict__ g2,
                                                 const float* __restrict__ gb,
                                                 const float* __restrict__ f1,
                                                 const float* __restrict__ f2,
                                                 float* __restrict__ out) {
  const int j = blockIdx.x * 256 + threadIdx.x;
  const int i0 = blockIdx.y * 4;
  if (j >= NT_) return;
  const float gbj = gb[j];
  #pragma unroll
  for (int r = 0; r < 4; ++r) {
    const int i = i0 + r;
    if (i >= NT_) break;
    const long long o = (long long)i * NP + j;
    const float t = g1[o] + g2[o] + gbj;
    const float g = 1.f / (1.f + __expf(-t));
    const long long oo = (long long)i * NT_ + j;
    out[oo] = (1.f - g) * f1[oo] + g * f2[oo];
  }
}

// zero head-pad cols of Q/K/V slots and tail cols of ctxp (once per call)
__global__ __launch_bounds__(256) void zero_pads(u16* __restrict__ qkv, u16* __restrict__ ctxp) {
  const int idx = blockIdx.x * 256 + threadIdx.x;
  if (idx < 41472) {
    const int buf = idx / 13824;
    const int r1 = idx % 13824;
    const int h = r1 / 4608;
    const int r2 = r1 % 4608;
    const int row = r2 / 3;
    const int c = DK + r2 % 3;
    qkv[(long long)buf * SZp + (long long)h * HS + (long long)row * DKP + c] = 0;
  } else {
    const int k = idx - 41472;
    const int row = k / 9;
    const int c = NT_ + k % 9;
    ctxp[(long long)row * NP + c] = 0;
  }
}

static inline GP mk() { GP p; memset(&p, 0, sizeof(p)); return p; }

extern "C" void kernel_launch(void* const* d_in, const int* in_sizes, int n_in,
                              void* d_out, int out_size, void* d_ws, size_t ws_size,
                              hipStream_t stream) {
  (void)in_sizes; (void)n_in; (void)out_size; (void)ws_size;
  const float* feature = (const float*)d_in[0];
  const float* faeture = (const float*)d_in[1];
  const float* Wq = (const float*)d_in[2];
  const float* bq = (const float*)d_in[3];
  const float* Wk = (const float*)d_in[4];
  const float* bk = (const float*)d_in[5];
  const float* Wv = (const float*)d_in[6];
  const float* bv = (const float*)d_in[7];
  const float* Wo = (const float*)d_in[8];
  const float* bo = (const float*)d_in[9];
  const float* gW = (const float*)d_in[10];
  const float* gb = (const float*)d_in[11];
  const float* etas = (const float*)d_in[12];
  float* out = (float*)d_out;

  // workspace map (peak ~82.7 MB)
  u16* ub = (u16*)d_ws;
  u16* slotA = ub + 0 * SZp;         // PT / Q[3 heads] / gate: feature bf16
  u16* slotB = ub + 1 * SZp;         // fT / K
  u16* slotC = ub + 2 * SZp;         // W1T / V
  u16* slotD = ub + 3 * SZp;         // W2T / V^T
  u16* Hb16  = ub + 4 * SZp;
  u16* ctxp  = ub + 5 * SZp;
  u16* Wb    = ub + 6 * SZp;         // 4 slots (Wq,Wk,Wv,Wo / G1,G2)
  float* fa = (float*)(ub + 10 * SZp);
  float* S0 = fa;                    // bf16 scores/attn (3 z-slices, u16 view) / gacc f32 x2
  u16* Sb = (u16*)fa;
  float* rg = fa + 3 * SZp;
  float* inv = fa + 4 * SZp;

  const float scale = 1.0f / sqrtf((float)DK);
  const dim3 blk(256);

  // ---- prep + RWR ----
  hipLaunchKernelGGL(rowsum_inv, dim3(NT_), blk, 0, stream, feature, inv);
  hipLaunchKernelGGL(prep_feat, dim3(6, 384), blk, 0, stream, feature, Hb16);
  hipLaunchKernelGGL(build_pt, dim3(48, 48), blk, 0, stream, feature, inv, slotA, slotB);
  {
    GP p = mk();  // W1T = 0.3*(E^T P) + 0.7*E^T
    p.A = slotB; p.lda = NP; p.B = slotA; p.ldb = NP; p.K = NP;
    p.C16 = slotC; p.fT = slotB;
    hipLaunchKernelGGL((mgemm<EP_W, 64, 64>), dim3(24, 24, 1), blk, 0, stream, p);
  }
  {
    GP p = mk();  // W2T = 0.3*(W1T P) + 0.7*E^T
    p.A = slotC; p.lda = NP; p.B = slotA; p.ldb = NP; p.K = NP;
    p.C16 = slotD; p.fT = slotB;
    hipLaunchKernelGGL((mgemm<EP_W, 64, 64>), dim3(24, 24, 1), blk, 0, stream, p);
  }
  hipLaunchKernelGGL(rg_elem, dim3(6, 384), blk, 0, stream, feature, slotC, slotD, etas, rg);
  hipLaunchKernelGGL(zero_pads, dim3(216), blk, 0, stream, slotA, ctxp);

  // ---- layers ----
  for (int l = 0; l < NL; ++l) {
    const long long wofs = (long long)l * WSZ;
    const long long bofs = (long long)l * NT_;
    hipLaunchKernelGGL(conv_w, dim3(6, 384, 4), blk, 0, stream,
                       Wq + wofs, Wk + wofs, Wv + wofs, Wo + wofs, NT_, Wb);
    {
      GP p = mk();  // Q,K,V = H @ W^T + b  -> head-split padded slots
      p.A = Hb16; p.sA = 0; p.lda = NP;
      p.B = Wb; p.sB = SZp; p.ldb = NP; p.K = NP;
      p.C16 = slotA;
      p.b0 = bq + bofs; p.b1 = bk + bofs; p.b2 = bv + bofs;
      hipLaunchKernelGGL((mgemm<EP_QKV, 128, 32>), dim3(12, 24, 3), blk, 0, stream, p);
    }
    {
      GP p = mk();  // S_h = bf16((Q_h K_h^T * scale) .* rg)
      p.A = slotA; p.sA = HS; p.lda = DKP;
      p.B = slotB; p.sB = HS; p.ldb = DKP; p.K = DKP;
      p.C16 = Sb; p.rg = rg; p.scale = scale;
      hipLaunchKernelGGL((mgemm<EP_SC, 128, 32>), dim3(12, 24, 3), blk, 0, stream, p);
    }
    hipLaunchKernelGGL(softmax_k, dim3(NP, 3), blk, 0, stream, Sb);
    hipLaunchKernelGGL(tr_b16, dim3(16, 48, 3), blk, 0, stream, slotC, slotD);
    {
      GP p = mk();  // ctx_h = attn_h @ V_h   (A = compact bf16 attn, B = V^T)
      p.A = Sb; p.sA = SZp; p.lda = NP;
      p.B = slotD; p.sB = HS; p.ldb = NP; p.K = NP;
      p.C16 = ctxp;
      hipLaunchKernelGGL((mgemm<EP_PV, 64, 64>), dim3(8, 24, 3), blk, 0, stream, p);
    }
    {
      GP p = mk();  // H = H + ctx @ Wo^T + bo  (in-place bf16 H)
      p.A = ctxp; p.sA = 0; p.lda = NP;
      p.B = Wb + 3 * SZp; p.sB = 0; p.ldb = NP; p.K = NP;
      p.C16 = Hb16; p.b0 = bo + bofs;
      hipLaunchKernelGGL((mgemm<EP_OP, 64, 64>), dim3(24, 24, 1), blk, 0, stream, p);
    }
  }

  // ---- gate (z=2 batched GEMM + elementwise blend) ----
  hipLaunchKernelGGL(conv_w, dim3(6, 384, 2), blk, 0, stream,
                     gW, gW + NT_, gW, gW, 2 * NT_, Wb);
  hipLaunchKernelGGL(prep_feat, dim3(6, 384), blk, 0, stream, feature, slotA);
  {
    GP p = mk();  // z0: H@G1^T -> S0[0] ; z1: feature@G2^T -> S0[1]
    p.A = Hb16; p.sA = -(4 * SZp); p.lda = NP;   // z=1 selects slotA
    p.B = Wb; p.sB = SZp; p.ldb = NP; p.K = NP;
    p.Cf = S0;
    hipLaunchKernelGGL((mgemm<EP_G1, 64, 64>), dim3(24, 24, 2), blk, 0, stream, p);
  }
  hipLaunchKernelGGL(gate_elem, dim3(6, 382), blk, 0, stream,
                     S0, S0 + SZp, gb, feature, faeture, out);
}